// Round 19
// baseline (137.343 us; speedup 1.0000x reference)
//
#include <hip/hip_runtime.h>
#include <hip/hip_bf16.h>
#include <stdint.h>

#define P    300
#define HID  128
#define NG   1000
#define NTL  19          // 16-node tiles (304 rows, 300 valid)

typedef __attribute__((ext_vector_type(8))) short bf16x8;
typedef __attribute__((ext_vector_type(4))) float f32x4;

__device__ __forceinline__ short f2bf(float f) {
    union { float f; uint32_t u; } v; v.f = f;
    uint32_t r = v.u + 0x7fffu + ((v.u >> 16) & 1u);   // RNE
    return (short)(r >> 16);
}
__device__ __forceinline__ uint32_t pkbf2(float a, float b) {   // low=a, high=b
    union { __hip_bfloat162 h; uint32_t u; } cv;
    cv.h = __float22bfloat162_rn(float2{a, b});
    return cv.u;
}

// ring-average + bias + relu over 4 consecutive node-rows (f32 in regs)
__device__ __forceinline__ void avg_epi(const f32x4 &G, float vp0, float vn3,
                                        float b, float* o) {
    o[0] = (vp0  + G[0] + G[1]) * (1.0f / 3.0f) + b;
    o[1] = (G[0] + G[1] + G[2]) * (1.0f / 3.0f) + b;
    o[2] = (G[1] + G[2] + G[3]) * (1.0f / 3.0f) + b;
    o[3] = (G[2] + G[3] + vn3 ) * (1.0f / 3.0f) + b;
    #pragma unroll
    for (int i = 0; i < 4; ++i) o[i] = o[i] > 0.f ? o[i] : 0.f;
}

// One GCN layer; 8 waves, wave wv owns ft-tile wv (1 ft-tile = 16
// features; fkey = wv*16+lm). Session-best structure (r13/r17: bench
// 121.6-121.7 us, k_graph ~50 us) with the k_prep launch deleted: wf
// fragments converted INLINE from the f32 weight matrix (same f2bf RNE
// -> bit-identical numerics).
// r18 BUG FIX: the logical k-chunk for wf[kk] is 4*kk+q (NO XOR). The
// (..^lm) XOR in r17 was the g_wsw STORAGE swizzle (bank-conflict
// avoidance in LDS-side layout); content chunk there was
// ((4*kk+q)^lm)^lm = 4*kk+q. Global f32 W has no swizzled layout --
// applying the XOR to the chunk index fetched wrong k-rows (absmax
// 3.2e-2). 16 lanes x consecutive fkey still give coalesced 64 B
// segments per (chunk,j); the 128 KB weight pair is L2/L3-resident.
// 3-PHASE / 2-BARRIER schedule (r4-proven race-free):
//   A: MFMA tiles {10..18, 0} -> GH (reads only); barrier
//   B: i=0..8: MFMA tile 9-i -> GL[i]; epi/store tiles 10..18, 0
//      (reads {9..1} vs stores {10..18,0}: DISJOINT); barrier
//   C: epi/store tiles 1..9 (stores only)
// Epilogue: RAW-F32 shuffles; vA = row above / r15-carry, vB = row
// below, vC = next-tile r0. Wraps: tile0.vp0(q0) = G18 r11 (lane
// 32+lm), tile18.vn3(q2) = G0 r0, tile0.vn3(q3) = G1 r0.
template<int POOL>
__device__ __forceinline__ void run_pass(short* __restrict__ buf,
                                         const float* __restrict__ Wf32,
                                         const float* __restrict__ bias,
                                         float* __restrict__ pool, int tid) {
    const int lane = tid & 63, wv = tid >> 6, q = lane >> 4, lm = lane & 15;
    const int fkey = wv * 16 + lm;            // this lane's feature
    bf16x8 wf[4];                             // wf[kk] = k-chunk 4*kk+q of col fkey
    #pragma unroll
    for (int kk = 0; kk < 4; ++kk) {
        const int chunk = 4 * kk + q;         // LOGICAL chunk -- no XOR (r18 fix)
        #pragma unroll
        for (int j = 0; j < 8; ++j)
            wf[kk][j] = f2bf(Wf32[(chunk * 8 + j) * HID + fkey]);
    }
    const float biaf = bias[fkey];
    const int kcs = fkey >> 3, offs = fkey & 7;
    const int sA = (q == 0) ? (48 + lm) : (lane - 16);  // r15 carry / row above
    const int sB = (lane + 16) & 63;                    // row below (q<3)

    float psum = 0.f;

    auto mfma_tile = [&](int t, f32x4 &G) {
        const short* tb = buf + t * 2048;
        G = f32x4{0.f, 0.f, 0.f, 0.f};
        #pragma unroll
        for (int kk = 0; kk < 4; ++kk) {
            // buf position (lm, (4*kk+q)^lm) holds content chunk 4*kk+q
            bf16x8 af = *(const bf16x8*)&tb[(lm * 16 + ((4 * kk + q) ^ lm)) * 8];
            G = __builtin_amdgcn_mfma_f32_16x16x32_bf16(af, wf[kk], G, 0, 0, 0);
        }
    };
    auto store_rows = [&](int T, float (&o)[4]) {
        uint32_t u01 = pkbf2(o[0], o[1]);
        uint32_t u23 = pkbf2(o[2], o[3]);
        int n0 = T * 16 + q * 4;
        buf[(n0 * 16       + (kcs ^ ( n0      & 15))) * 8 + offs] = (short)u01;
        buf[((n0 + 1) * 16 + (kcs ^ ((n0 + 1) & 15))) * 8 + offs] = (short)(u01 >> 16);
        buf[((n0 + 2) * 16 + (kcs ^ ((n0 + 2) & 15))) * 8 + offs] = (short)u23;
        buf[((n0 + 3) * 16 + (kcs ^ ((n0 + 3) & 15))) * 8 + offs] = (short)(u23 >> 16);
    };
    auto accum = [&](float (&o)[4]) { psum += o[0] + o[1] + o[2] + o[3]; };

    float c15;
    // mid-ring epilogue of tile with centers E; N0 = next tile's G[0]
    auto epi_mid = [&](const f32x4 &E, float N0, float (&o)[4]) {
        float vA = __shfl(E[3], sA, 64);
        float vB = __shfl(E[0], sB, 64);
        float vC = __shfl(N0, lm, 64);
        float vp0 = (q == 0) ? c15 : vA;
        float vn3 = (q == 3) ? vC : vB;
        avg_epi(E, vp0, vn3, biaf, o);
        c15 = vA;                 // this tile's r15 -> next tile's vp0(q==0)
    };

    f32x4 GH[10];   // GH[k] = G[10+k] for k<9; GH[9] = G[0]
    f32x4 GL[9];    // GL[i] = G[9-i]

    // ---- phase A: MFMA tiles 10..18 and 0 (reads only) ----
    #pragma unroll
    for (int k = 0; k < 9; ++k) mfma_tile(10 + k, GH[k]);
    mfma_tile(0, GH[9]);
    if (!POOL) __syncthreads();

    // ---- phase B: MFMA 9..1 interleaved with epi/store of 10..18, 0 ----
    #pragma unroll
    for (int i = 0; i < 9; ++i) {
        mfma_tile(9 - i, GL[i]);
        if (i == 0) c15 = __shfl(GL[0][3], 48 + lm, 64);   // G9 r15 (node 159)
        if (i < 8) {
            float o[4];
            epi_mid(GH[i], GH[i + 1][0], o);
            if (POOL) accum(o); else store_rows(10 + i, o);
        } else {
            // tile 18 (rows 288..299 valid; row299.next = node0)
            float o18[4];
            {
                float vA = __shfl(GH[8][3], sA, 64);
                float vB = __shfl(GH[8][0], sB, 64);
                float vZ = __shfl(GH[9][0], lm, 64);       // G0 r0 (node 0)
                float vp0 = (q == 0) ? c15 : vA;
                float vn3 = (q == 2) ? vZ : vB;
                avg_epi(GH[8], vp0, vn3, biaf, o18);
            }
            if (q < 3) { if (POOL) accum(o18); else store_rows(18, o18); }
            // tile 0 (row0.prev = node299 = G18 r11; row15.next = G1 r0)
            float o0[4];
            {
                float vA0 = __shfl(GH[9][3], (lane - 16) & 63, 64);
                float vB0 = __shfl(GH[9][0], sB, 64);
                float vP  = __shfl(GH[8][3], 32 + lm, 64); // G18 r11 (node 299)
                float vN  = __shfl(GL[8][0], lm, 64);      // G1 r0 (node 16)
                float vp0 = (q == 0) ? vP : vA0;
                float vn3 = (q == 3) ? vN : vB0;
                avg_epi(GH[9], vp0, vn3, biaf, o0);
            }
            if (POOL) accum(o0); else store_rows(0, o0);
        }
    }
    if (!POOL) __syncthreads();

    // ---- phase C: epi/store tiles 1..9 (stores only) ----
    c15 = __shfl(GH[9][3], 48 + lm, 64);                   // G0 r15 (node 15)
    #pragma unroll
    for (int T = 1; T <= 9; ++T) {
        float o[4];
        float N0 = (T < 9) ? GL[8 - T][0] : GH[0][0];      // next tile's r0
        epi_mid(GL[9 - T], N0, o);
        if (POOL) accum(o); else store_rows(T, o);
    }

    if (POOL) {
        psum += __shfl_xor(psum, 16, 64);
        psum += __shfl_xor(psum, 32, 64);
        if (q == 0) pool[fkey] = psum;
    }
}

// One block (512 thr, 8 waves) per graph, feature-split, SINGLE LAUNCH.
// LDS 80384 B (HW-proven 2/CU) -> 16 waves/CU = 4 waves/SIMD. Register
// gate (r9/r10): 2 blocks/CU needs COMBINED VGPR+AGPR <= 128/wave. Live
// set: GH+GL 76 + wf 16 + temps ~25 = ~117. (512,2) caps arch at 128.
__global__ __launch_bounds__(512, 2) void k_graph(
        const float* __restrict__ x,
        const float* __restrict__ W1,  const float* __restrict__ b1,
        const float* __restrict__ W2,  const float* __restrict__ b2v,
        const float* __restrict__ W3,  const float* __restrict__ b3v,
        const float* __restrict__ fw1, const float* __restrict__ fb1,
        const float* __restrict__ fw2, const float* __restrict__ fb2,
        float* __restrict__ out) {
    __shared__ __align__(16) short buf[304 * HID];   // 77824 B, chunk-swizzled
    __shared__ __align__(16) float scr[640];         // 2560 B -> total 80384
    float* xs    = scr;          // 600 (layer-1 only, dead after)
    float* pool  = scr;          // 128
    float* parts = scr + 128;    // 256
    float* s1    = scr + 384;    // 128

    const int g = blockIdx.x, tid = threadIdx.x;

    if (tid < 150) *(float4*)&xs[tid * 4] = *(const float4*)&x[g * 600 + tid * 4];
    __syncthreads();

    // ---- layer 1: buf <- relu(avg3(x) @ W1 + b1); rows 300..303 zeroed ----
    {
        const int kc1 = tid & 15;
        const int n0  = tid >> 4;            // 0..31
        float w1x[8], w1y[8], b1v[8];
        #pragma unroll
        for (int j = 0; j < 8; ++j) {
            w1x[j] = W1[kc1 * 8 + j];
            w1y[j] = W1[HID + kc1 * 8 + j];
            b1v[j] = b1[kc1 * 8 + j];
        }
        #pragma unroll
        for (int it = 0; it < 10; ++it) {
            int node = it * 32 + n0;         // 0..319
            if (node < 304) {
                uint32_t w[4] = {0u, 0u, 0u, 0u};
                if (node < P) {
                    int prev = (node == 0)     ? P - 1 : node - 1;
                    int next = (node == P - 1) ? 0     : node + 1;
                    float2 xp = *(const float2*)&xs[2 * prev];
                    float2 xc = *(const float2*)&xs[2 * node];
                    float2 xn = *(const float2*)&xs[2 * next];
                    float ax = (xp.x + xc.x + xn.x) * (1.f / 3.f);
                    float ay = (xp.y + xc.y + xn.y) * (1.f / 3.f);
                    #pragma unroll
                    for (int jj = 0; jj < 4; ++jj) {
                        float va = ax * w1x[2*jj]   + ay * w1y[2*jj]   + b1v[2*jj];
                        float vb = ax * w1x[2*jj+1] + ay * w1y[2*jj+1] + b1v[2*jj+1];
                        va = va > 0.f ? va : 0.f;
                        vb = vb > 0.f ? vb : 0.f;
                        w[jj] = pkbf2(va, vb);
                    }
                }
                *(uint4*)&buf[(node * 16 + (kc1 ^ (node & 15))) * 8] =
                    uint4{w[0], w[1], w[2], w[3]};
            }
        }
    }
    __syncthreads();

    run_pass<0>(buf, W2, b2v, pool, tid);   // h1 -> h2 in place
    __syncthreads();
    run_pass<1>(buf, W3, b3v, pool, tid);   // h2 -> pooled sums
    __syncthreads();

    // ---- FC head (tiny; 256 active threads) ----
    if (tid < 256) {
        int f = tid & 127, half = tid >> 7;
        float p = 0.f;
        const float* fw1c = fw1 + f;
        #pragma unroll 4
        for (int k = half * 64; k < half * 64 + 64; ++k)
            p += pool[k] * fw1c[k * 128];
        parts[half * 128 + f] = p;
    }
    __syncthreads();
    if (tid < 128) {
        float o1 = fb1[tid] + (parts[tid] + parts[128 + tid]) * (1.0f / 300.0f);
        s1[tid] = o1 > 0.f ? o1 : 0.f;
    }
    __syncthreads();
    if (tid < 128) {
        int o = tid >> 6, ln = tid & 63;
        float v = s1[ln] * fw2[ln * 2 + o] + s1[ln + 64] * fw2[(ln + 64) * 2 + o];
        #pragma unroll
        for (int off = 1; off <= 32; off <<= 1)
            v += __shfl_xor(v, off, 64);
        if (ln == 0) out[g * 2 + o] = v + fb2[o];
    }
}

extern "C" void kernel_launch(void* const* d_in, const int* in_sizes, int n_in,
                              void* d_out, int out_size, void* d_ws, size_t ws_size,
                              hipStream_t stream) {
    const float* x   = (const float*)d_in[0];
    const float* W1  = (const float*)d_in[3];
    const float* b1  = (const float*)d_in[4];
    const float* W2  = (const float*)d_in[5];
    const float* b2  = (const float*)d_in[6];
    const float* W3  = (const float*)d_in[7];
    const float* b3  = (const float*)d_in[8];
    const float* fw1 = (const float*)d_in[9];
    const float* fb1 = (const float*)d_in[10];
    const float* fw2 = (const float*)d_in[11];
    const float* fb2 = (const float*)d_in[12];
    float* out = (float*)d_out;

    k_graph<<<dim3(NG), dim3(512), 0, stream>>>(x, W1, b1, W2, b2, W3, b3,
                                                fw1, fb1, fw2, fb2, out);
}

// Round 20
// 120.819 us; speedup vs baseline: 1.1368x; 1.1368x over previous
//
#include <hip/hip_runtime.h>
#include <hip/hip_bf16.h>
#include <stdint.h>

#define P    300
#define HID  128
#define NG   1000
#define NTL  19          // 16-node tiles (304 rows, 300 valid)

typedef __attribute__((ext_vector_type(8))) short bf16x8;
typedef __attribute__((ext_vector_type(4))) float f32x4;

// Swizzled bf16 W^T, NATURAL feature order both layers (1-ft/wave needs
// no store-pairing permutation). chunk(fkey,kc) at fkey*16+(kc^(fkey&15)).
// k_prep is retained deliberately: r19 measured that inlining this
// conversion into k_graph costs +12 arch VGPR -> crosses the combined
// VGPR+AGPR <= 128 residency gate -> 1 block/CU -> kernel +19 us, far
// exceeding the ~10 us saved by dropping the launch.
__device__ short g_wsw[2 * HID * HID];

__device__ __forceinline__ short f2bf(float f) {
    union { float f; uint32_t u; } v; v.f = f;
    uint32_t r = v.u + 0x7fffu + ((v.u >> 16) & 1u);   // RNE
    return (short)(r >> 16);
}
__device__ __forceinline__ uint32_t pkbf2(float a, float b) {   // low=a, high=b
    union { __hip_bfloat162 h; uint32_t u; } cv;
    cv.h = __float22bfloat162_rn(float2{a, b});
    return cv.u;
}

__global__ __launch_bounds__(256) void k_prep(const float* __restrict__ W2,
                                              const float* __restrict__ W3) {
    int b = blockIdx.x;                       // 16 blocks
    const float* W = (b < 8) ? W2 : W3;
    short* dst = g_wsw + ((b < 8) ? 0 : HID * HID);
    int t    = (b & 7) * 256 + threadIdx.x;   // 0..2047 chunks
    int fkey = t >> 4;
    int kc   = t & 15;
    bf16x8 o;
    #pragma unroll
    for (int j = 0; j < 8; ++j)
        o[j] = f2bf(W[(kc * 8 + j) * HID + fkey]);
    *(bf16x8*)&dst[(fkey * 16 + (kc ^ (fkey & 15))) * 8] = o;
}

// ring-average + bias + relu over 4 consecutive node-rows (f32 in regs)
__device__ __forceinline__ void avg_epi(const f32x4 &G, float vp0, float vn3,
                                        float b, float* o) {
    o[0] = (vp0  + G[0] + G[1]) * (1.0f / 3.0f) + b;
    o[1] = (G[0] + G[1] + G[2]) * (1.0f / 3.0f) + b;
    o[2] = (G[1] + G[2] + G[3]) * (1.0f / 3.0f) + b;
    o[3] = (G[2] + G[3] + vn3 ) * (1.0f / 3.0f) + b;
    #pragma unroll
    for (int i = 0; i < 4; ++i) o[i] = o[i] > 0.f ? o[i] : 0.f;
}

// One GCN layer; 8 waves, wave wv owns ft-tile wv (1 ft-tile = 16
// features; fkey = wv*16+lm). SESSION-BEST configuration (r13/r17:
// bench 121.6/121.7 us, k_graph ~50 us; reproduced twice).
// 3-PHASE / 2-BARRIER schedule (r4-proven race-free):
//   A: MFMA tiles {10..18, 0} -> GH (reads only); barrier
//   B: i=0..8: MFMA tile 9-i -> GL[i]; epi/store tiles 10..18, 0
//      (reads {9..1} vs stores {10..18,0}: DISJOINT); barrier
//   C: epi/store tiles 1..9 (stores only)
// Epilogue: RAW-F32 shuffles; vA = row above / r15-carry, vB = row
// below, vC = next-tile r0. Wraps: tile0.vp0(q0) = G18 r11 (lane
// 32+lm), tile18.vn3(q2) = G0 r0, tile0.vn3(q3) = G1 r0.
template<int POOL>
__device__ __forceinline__ void run_pass(short* __restrict__ buf,
                                         const short* __restrict__ wbase,
                                         const float* __restrict__ bias,
                                         float* __restrict__ pool, int tid) {
    const int lane = tid & 63, wv = tid >> 6, q = lane >> 4, lm = lane & 15;
    const int fkey = wv * 16 + lm;            // this lane's feature
    bf16x8 wf[4];
    #pragma unroll
    for (int kk = 0; kk < 4; ++kk)
        wf[kk] = *(const bf16x8*)&wbase[(fkey * 16 + ((4 * kk + q) ^ lm)) * 8];
    const float biaf = bias[fkey];
    const int kcs = fkey >> 3, offs = fkey & 7;
    const int sA = (q == 0) ? (48 + lm) : (lane - 16);  // r15 carry / row above
    const int sB = (lane + 16) & 63;                    // row below (q<3)

    float psum = 0.f;

    auto mfma_tile = [&](int t, f32x4 &G) {
        const short* tb = buf + t * 2048;
        G = f32x4{0.f, 0.f, 0.f, 0.f};
        #pragma unroll
        for (int kk = 0; kk < 4; ++kk) {
            bf16x8 af = *(const bf16x8*)&tb[(lm * 16 + ((4 * kk + q) ^ lm)) * 8];
            G = __builtin_amdgcn_mfma_f32_16x16x32_bf16(af, wf[kk], G, 0, 0, 0);
        }
    };
    auto store_rows = [&](int T, float (&o)[4]) {
        uint32_t u01 = pkbf2(o[0], o[1]);
        uint32_t u23 = pkbf2(o[2], o[3]);
        int n0 = T * 16 + q * 4;
        buf[(n0 * 16       + (kcs ^ ( n0      & 15))) * 8 + offs] = (short)u01;
        buf[((n0 + 1) * 16 + (kcs ^ ((n0 + 1) & 15))) * 8 + offs] = (short)(u01 >> 16);
        buf[((n0 + 2) * 16 + (kcs ^ ((n0 + 2) & 15))) * 8 + offs] = (short)u23;
        buf[((n0 + 3) * 16 + (kcs ^ ((n0 + 3) & 15))) * 8 + offs] = (short)(u23 >> 16);
    };
    auto accum = [&](float (&o)[4]) { psum += o[0] + o[1] + o[2] + o[3]; };

    float c15;
    // mid-ring epilogue of tile with centers E; N0 = next tile's G[0]
    auto epi_mid = [&](const f32x4 &E, float N0, float (&o)[4]) {
        float vA = __shfl(E[3], sA, 64);
        float vB = __shfl(E[0], sB, 64);
        float vC = __shfl(N0, lm, 64);
        float vp0 = (q == 0) ? c15 : vA;
        float vn3 = (q == 3) ? vC : vB;
        avg_epi(E, vp0, vn3, biaf, o);
        c15 = vA;                 // this tile's r15 -> next tile's vp0(q==0)
    };

    f32x4 GH[10];   // GH[k] = G[10+k] for k<9; GH[9] = G[0]
    f32x4 GL[9];    // GL[i] = G[9-i]

    // ---- phase A: MFMA tiles 10..18 and 0 (reads only) ----
    #pragma unroll
    for (int k = 0; k < 9; ++k) mfma_tile(10 + k, GH[k]);
    mfma_tile(0, GH[9]);
    if (!POOL) __syncthreads();

    // ---- phase B: MFMA 9..1 interleaved with epi/store of 10..18, 0 ----
    #pragma unroll
    for (int i = 0; i < 9; ++i) {
        mfma_tile(9 - i, GL[i]);
        if (i == 0) c15 = __shfl(GL[0][3], 48 + lm, 64);   // G9 r15 (node 159)
        if (i < 8) {
            float o[4];
            epi_mid(GH[i], GH[i + 1][0], o);
            if (POOL) accum(o); else store_rows(10 + i, o);
        } else {
            // tile 18 (rows 288..299 valid; row299.next = node0)
            float o18[4];
            {
                float vA = __shfl(GH[8][3], sA, 64);
                float vB = __shfl(GH[8][0], sB, 64);
                float vZ = __shfl(GH[9][0], lm, 64);       // G0 r0 (node 0)
                float vp0 = (q == 0) ? c15 : vA;
                float vn3 = (q == 2) ? vZ : vB;
                avg_epi(GH[8], vp0, vn3, biaf, o18);
            }
            if (q < 3) { if (POOL) accum(o18); else store_rows(18, o18); }
            // tile 0 (row0.prev = node299 = G18 r11; row15.next = G1 r0)
            float o0[4];
            {
                float vA0 = __shfl(GH[9][3], (lane - 16) & 63, 64);
                float vB0 = __shfl(GH[9][0], sB, 64);
                float vP  = __shfl(GH[8][3], 32 + lm, 64); // G18 r11 (node 299)
                float vN  = __shfl(GL[8][0], lm, 64);      // G1 r0 (node 16)
                float vp0 = (q == 0) ? vP : vA0;
                float vn3 = (q == 3) ? vN : vB0;
                avg_epi(GH[9], vp0, vn3, biaf, o0);
            }
            if (POOL) accum(o0); else store_rows(0, o0);
        }
    }
    if (!POOL) __syncthreads();

    // ---- phase C: epi/store tiles 1..9 (stores only) ----
    c15 = __shfl(GH[9][3], 48 + lm, 64);                   // G0 r15 (node 15)
    #pragma unroll
    for (int T = 1; T <= 9; ++T) {
        float o[4];
        float N0 = (T < 9) ? GL[8 - T][0] : GH[0][0];      // next tile's r0
        epi_mid(GL[9 - T], N0, o);
        if (POOL) accum(o); else store_rows(T, o);
    }

    if (POOL) {
        psum += __shfl_xor(psum, 16, 64);
        psum += __shfl_xor(psum, 32, 64);
        if (q == 0) pool[fkey] = psum;
    }
}

// One block (512 thr, 8 waves) per graph, feature-split. LDS 80384 B
// (HW-proven 2/CU) -> 16 waves/CU = 4 waves/SIMD. Register gate (r9/r10/
// r19 evidence): 2 blocks/CU needs COMBINED VGPR+AGPR <= 128/wave. Live
// set here: arch 64 + acc ~52 = ~116, fits. (512,2) caps arch at 128.
__global__ __launch_bounds__(512, 2) void k_graph(
        const float* __restrict__ x,
        const float* __restrict__ W1,  const float* __restrict__ b1,
        const float* __restrict__ b2v, const float* __restrict__ b3v,
        const float* __restrict__ fw1, const float* __restrict__ fb1,
        const float* __restrict__ fw2, const float* __restrict__ fb2,
        float* __restrict__ out) {
    __shared__ __align__(16) short buf[304 * HID];   // 77824 B, chunk-swizzled
    __shared__ __align__(16) float scr[640];         // 2560 B -> total 80384
    float* xs    = scr;          // 600 (layer-1 only, dead after)
    float* pool  = scr;          // 128
    float* parts = scr + 128;    // 256
    float* s1    = scr + 384;    // 128

    const int g = blockIdx.x, tid = threadIdx.x;

    if (tid < 150) *(float4*)&xs[tid * 4] = *(const float4*)&x[g * 600 + tid * 4];
    __syncthreads();

    // ---- layer 1: buf <- relu(avg3(x) @ W1 + b1); rows 300..303 zeroed ----
    {
        const int kc1 = tid & 15;
        const int n0  = tid >> 4;            // 0..31
        float w1x[8], w1y[8], b1v[8];
        #pragma unroll
        for (int j = 0; j < 8; ++j) {
            w1x[j] = W1[kc1 * 8 + j];
            w1y[j] = W1[HID + kc1 * 8 + j];
            b1v[j] = b1[kc1 * 8 + j];
        }
        #pragma unroll
        for (int it = 0; it < 10; ++it) {
            int node = it * 32 + n0;         // 0..319
            if (node < 304) {
                uint32_t w[4] = {0u, 0u, 0u, 0u};
                if (node < P) {
                    int prev = (node == 0)     ? P - 1 : node - 1;
                    int next = (node == P - 1) ? 0     : node + 1;
                    float2 xp = *(const float2*)&xs[2 * prev];
                    float2 xc = *(const float2*)&xs[2 * node];
                    float2 xn = *(const float2*)&xs[2 * next];
                    float ax = (xp.x + xc.x + xn.x) * (1.f / 3.f);
                    float ay = (xp.y + xc.y + xn.y) * (1.f / 3.f);
                    #pragma unroll
                    for (int jj = 0; jj < 4; ++jj) {
                        float va = ax * w1x[2*jj]   + ay * w1y[2*jj]   + b1v[2*jj];
                        float vb = ax * w1x[2*jj+1] + ay * w1y[2*jj+1] + b1v[2*jj+1];
                        va = va > 0.f ? va : 0.f;
                        vb = vb > 0.f ? vb : 0.f;
                        w[jj] = pkbf2(va, vb);
                    }
                }
                *(uint4*)&buf[(node * 16 + (kc1 ^ (node & 15))) * 8] =
                    uint4{w[0], w[1], w[2], w[3]};
            }
        }
    }
    __syncthreads();

    run_pass<0>(buf, g_wsw,             b2v, pool, tid);   // h1 -> h2 in place
    __syncthreads();
    run_pass<1>(buf, g_wsw + HID * HID, b3v, pool, tid);   // h2 -> pooled sums
    __syncthreads();

    // ---- FC head (tiny; 256 active threads) ----
    if (tid < 256) {
        int f = tid & 127, half = tid >> 7;
        float p = 0.f;
        const float* fw1c = fw1 + f;
        #pragma unroll 4
        for (int k = half * 64; k < half * 64 + 64; ++k)
            p += pool[k] * fw1c[k * 128];
        parts[half * 128 + f] = p;
    }
    __syncthreads();
    if (tid < 128) {
        float o1 = fb1[tid] + (parts[tid] + parts[128 + tid]) * (1.0f / 300.0f);
        s1[tid] = o1 > 0.f ? o1 : 0.f;
    }
    __syncthreads();
    if (tid < 128) {
        int o = tid >> 6, ln = tid & 63;
        float v = s1[ln] * fw2[ln * 2 + o] + s1[ln + 64] * fw2[(ln + 64) * 2 + o];
        #pragma unroll
        for (int off = 1; off <= 32; off <<= 1)
            v += __shfl_xor(v, off, 64);
        if (ln == 0) out[g * 2 + o] = v + fb2[o];
    }
}

extern "C" void kernel_launch(void* const* d_in, const int* in_sizes, int n_in,
                              void* d_out, int out_size, void* d_ws, size_t ws_size,
                              hipStream_t stream) {
    const float* x   = (const float*)d_in[0];
    const float* W1  = (const float*)d_in[3];
    const float* b1  = (const float*)d_in[4];
    const float* W2  = (const float*)d_in[5];
    const float* b2  = (const float*)d_in[6];
    const float* W3  = (const float*)d_in[7];
    const float* b3  = (const float*)d_in[8];
    const float* fw1 = (const float*)d_in[9];
    const float* fb1 = (const float*)d_in[10];
    const float* fw2 = (const float*)d_in[11];
    const float* fb2 = (const float*)d_in[12];
    float* out = (float*)d_out;

    k_prep <<<dim3(16), dim3(256), 0, stream>>>(W2, W3);
    k_graph<<<dim3(NG), dim3(512), 0, stream>>>(x, W1, b1, b2, b3,
                                                fw1, fb1, fw2, fb2, out);
}